// Round 6
// baseline (15602.290 us; speedup 1.0000x reference)
//
#include <hip/hip_runtime.h>

typedef unsigned short ushort_t;
typedef __attribute__((ext_vector_type(8))) __bf16 bf16x8;
typedef __attribute__((ext_vector_type(4))) float f32x4;

#define MFMA_B16(a,b,c) __builtin_amdgcn_mfma_f32_16x16x32_bf16(a,b,c,0,0,0)

static constexpr int BATCH = 1024;
static constexpr int TT = 128;   // T
static constexpr int NN = 128;   // N
static constexpr int MM = 256;   // M == P
static constexpr int ERW = 648;  // enc state row width (ushorts): h256|c256|x128|pad8
static constexpr int DRW = 520;  // dec state row width: d256|s256|pad8

__device__ __forceinline__ float bf2f(ushort_t u) {
    union { unsigned int i; float f; } v;
    v.i = ((unsigned int)u) << 16;
    return v.f;
}
__device__ __forceinline__ ushort_t f2bf(float f) {
    union { unsigned int i; float f; } v;
    v.f = f;
    unsigned int i = v.i;
    return (ushort_t)((i + 0x7FFFu + ((i >> 16) & 1u)) >> 16);
}
// 16B-aligned load of 8 bf16 as MFMA operand
__device__ __forceinline__ bf16x8 ld_bf8(const ushort_t* p) {
    return __builtin_bit_cast(bf16x8, *(const int4*)p);
}
__device__ __forceinline__ void unp8(const int4 w, float* o) {
    union { unsigned int i; float f; } v;
    v.i = ((unsigned int)w.x) << 16;         o[0] = v.f;
    v.i = ((unsigned int)w.x) & 0xffff0000u; o[1] = v.f;
    v.i = ((unsigned int)w.y) << 16;         o[2] = v.f;
    v.i = ((unsigned int)w.y) & 0xffff0000u; o[3] = v.f;
    v.i = ((unsigned int)w.z) << 16;         o[4] = v.f;
    v.i = ((unsigned int)w.z) & 0xffff0000u; o[5] = v.f;
    v.i = ((unsigned int)w.w) << 16;         o[6] = v.f;
    v.i = ((unsigned int)w.w) & 0xffff0000u; o[7] = v.f;
}
// inf-safe without clamps: __fdividef(2,inf)=0, exp underflow->0
__device__ __forceinline__ float tanh_fast(float x) {
    float e = __expf(2.0f * x);
    return 1.0f - __fdividef(2.0f, e + 1.0f);
}
__device__ __forceinline__ float sig_fast(float x) {
    return __fdividef(1.0f, 1.0f + __expf(-x));
}

// ---------------------------------------------------------------------------
// Generic tiled GEMM (verified R1) — only for the two one-time precomputes.
// ---------------------------------------------------------------------------
template<bool WBF16, bool TRANSW, bool CBF16, bool RELU>
__global__ __launch_bounds__(256) void gemm_k(
    const float* __restrict__ A1, int lda1, long sA1z, int K1,
    const float* __restrict__ A2, int lda2, int K2,
    const void* __restrict__ W1v, int ldw1, long sW1z,
    const void* __restrict__ W2v, int ldw2,
    const float* __restrict__ bias1,
    void* __restrict__ Cv, int ldc, long sCz)
{
    __shared__ float As[32][68];
    __shared__ float Ws[32][68];
    const int tid = threadIdx.x;
    const int z = blockIdx.z;
    const int m0 = blockIdx.y * 64;
    const int g0 = blockIdx.x * 64;
    const int tm = tid & 15, tn = tid >> 4;
    float acc[4][4];
#pragma unroll
    for (int i = 0; i < 4; ++i)
#pragma unroll
        for (int j = 0; j < 4; ++j) acc[i][j] = 0.0f;

    for (int phase = 0; phase < 2; ++phase) {
        const float* A = (phase == 0) ? (A1 + (long)z * sA1z) : A2;
        const int lda = (phase == 0) ? lda1 : lda2;
        const int K = (phase == 0) ? K1 : K2;
        const int ldw = (phase == 0) ? ldw1 : ldw2;
        const void* Wv = (phase == 0) ? W1v : W2v;
        const long woff = (phase == 0) ? (long)z * sW1z : 0;
        if (A == nullptr || Wv == nullptr || K <= 0) continue;

        for (int k0 = 0; k0 < K; k0 += 32) {
            const int rem = K - k0;
            {
                const int tr0 = tid >> 3;
                const int tk = (tid & 7) * 4;
#pragma unroll
                for (int pass = 0; pass < 2; ++pass) {
                    const int m = tr0 + pass * 32;
                    const float* p = A + (long)(m0 + m) * lda + k0 + tk;
#pragma unroll
                    for (int j = 0; j < 4; ++j) {
                        float v = 0.0f;
                        if (tk + j < rem) v = p[j];
                        As[tk + j][m] = v;
                    }
                }
            }
            if constexpr (TRANSW) {
                const float* W = (const float*)Wv + woff;
                const int gq = (tid & 15) * 4;
                const int kr = tid >> 4;
#pragma unroll
                for (int pass = 0; pass < 2; ++pass) {
                    const int k = kr + pass * 16;
                    const float* p = W + (long)(k0 + k) * ldw + g0 + gq;
                    const bool ok = (k < rem);
#pragma unroll
                    for (int j = 0; j < 4; ++j) {
                        float v = 0.0f;
                        if (ok) v = p[j];
                        Ws[k][gq + j] = v;
                    }
                }
            } else if constexpr (WBF16) {
                const ushort_t* W = (const ushort_t*)Wv + woff;
                const int g = tid >> 2;
                const int tk = (tid & 3) * 8;
                const ushort_t* p = W + (long)(g0 + g) * ldw + k0 + tk;
#pragma unroll
                for (int j = 0; j < 8; ++j) {
                    float v = 0.0f;
                    if (tk + j < rem) v = bf2f(p[j]);
                    Ws[tk + j][g] = v;
                }
            } else {
                const float* W = (const float*)Wv + woff;
                const int tr0 = tid >> 3;
                const int tk = (tid & 7) * 4;
#pragma unroll
                for (int pass = 0; pass < 2; ++pass) {
                    const int g = tr0 + pass * 32;
                    const float* p = W + (long)(g0 + g) * ldw + k0 + tk;
#pragma unroll
                    for (int j = 0; j < 4; ++j) {
                        float v = 0.0f;
                        if (tk + j < rem) v = p[j];
                        Ws[tk + j][g] = v;
                    }
                }
            }
            __syncthreads();
#pragma unroll
            for (int kk = 0; kk < 32; ++kk) {
                const float4 av = *(const float4*)&As[kk][tm * 4];
                const float4 bv = *(const float4*)&Ws[kk][tn * 4];
                const float a[4] = {av.x, av.y, av.z, av.w};
                const float b[4] = {bv.x, bv.y, bv.z, bv.w};
#pragma unroll
                for (int i = 0; i < 4; ++i)
#pragma unroll
                    for (int j = 0; j < 4; ++j)
                        acc[i][j] = fmaf(a[i], b[j], acc[i][j]);
            }
            __syncthreads();
        }
    }
#pragma unroll
    for (int i = 0; i < 4; ++i) {
        const long m = m0 + tm * 4 + i;
#pragma unroll
        for (int j = 0; j < 4; ++j) {
            const int g = g0 + tn * 4 + j;
            float v = acc[i][j];
            if (bias1) v += bias1[g];
            if (RELU) v = fmaxf(v, 0.0f);
            if constexpr (CBF16)
                ((ushort_t*)Cv)[(long)z * sCz + m * ldc + g] = f2bf(v);
            else
                ((float*)Cv)[(long)z * sCz + m * ldc + g] = v;
        }
    }
}

// ---------------------------------------------------------------------------
// Pack fp32 weights into bf16 MFMA A-operand fragments.
// frag[((kb*NT + nt)*64 + l)*8 + j] = W[g][k], k = kb*32+(l>>4)*8+j,
// g = mode ? gatemap(nt, l&15) : nt*16 + (l&15).
// ---------------------------------------------------------------------------
__global__ void pack_frag_k(const float* __restrict__ W1, int ld1, int K1,
                            const float* __restrict__ W2, int ld2,
                            int Ktot, int NT, int mode,
                            ushort_t* __restrict__ dst)
{
    const int idx = blockIdx.x * 256 + threadIdx.x;
    const int total = Ktot * NT * 16;
    if (idx >= total) return;
    const int j = idx & 7, l = (idx >> 3) & 63, rest = idx >> 9;
    const int nt = rest % NT, kb = rest / NT;
    const int c = l & 15;
    const int k = kb * 32 + (l >> 4) * 8 + j;
    int g;
    if (mode) {
        const int w = nt >> 3, tt = nt & 7, q = tt >> 1, uh = tt & 1;
        g = q * 256 + w * 32 + uh * 16 + c;
    } else {
        g = nt * 16 + c;
    }
    const float v = (k < K1) ? W1[(long)g * ld1 + k] : W2[(long)g * ld2 + (k - K1)];
    dst[idx] = f2bf(v);
}

__global__ void prep_misc_k(const float* __restrict__ ebih, const float* __restrict__ ebhh,
                            const float* __restrict__ dbih, const float* __restrict__ dbhh,
                            const float* __restrict__ dWih,
                            float* __restrict__ ebsum, float* __restrict__ dbsum,
                            float* __restrict__ wy)
{
    const int i = blockIdx.x * 256 + threadIdx.x;
    if (i < 1024) {
        ebsum[i] = ebih[i] + ebhh[i];
        dbsum[i] = dbih[i] + dbhh[i];
        const int q = i & 3, u = i >> 2;
        wy[i] = dWih[q * 256 + u];
    }
}

__global__ void transpose_k(const float* __restrict__ src, float* __restrict__ dst,
                            int R, int C) {
    int i = blockIdx.x * 256 + threadIdx.x;
    if (i < R * C) { int r = i / C, c = i - r * C; dst[c * R + r] = src[i]; }
}

// ---------------------------------------------------------------------------
// Persistent encoder: 256 blocks x 512 threads, 4 rows/block.
// wq + gates via MFMA (weights bf16 frags, states bf16 hi/lo in LDS).
// ---------------------------------------------------------------------------
__global__ __launch_bounds__(512) void enc_persist(
    const float* __restrict__ enc_data,   // [1024][128][128]
    const ushort_t* __restrict__ D,       // [1024][128][128] bf16
    const ushort_t* __restrict__ WqeF,    // wq frags: 16kb x 8nt
    const ushort_t* __restrict__ GeF,     // gate frags: 12kb x 64nt
    const float* __restrict__ ebsum,      // [1024]
    const float* __restrict__ ve,         // [128]
    ushort_t* __restrict__ Hbf)           // [1024][128][256] bf16
{
    const int tid = threadIdx.x;
    const int b0 = blockIdx.x * 4;
    const int w = tid >> 6, l = tid & 63;
    const int r_ = l & 15, kq = l >> 4;
    __shared__ __align__(16) ushort_t sd_hi[16][ERW];
    __shared__ __align__(16) ushort_t sd_lo[16][ERW];
    __shared__ __align__(16) float wqs[128][4];
    __shared__ __align__(16) float scp[8][4][128];
    __shared__ float ves[128];

    if (tid < 128) ves[tid] = ve[tid];
    for (int i = tid; i < 16 * ERW / 2; i += 512) {
        ((unsigned int*)sd_hi)[i] = 0u;
        ((unsigned int*)sd_lo)[i] = 0u;
    }
    float cell[2][4] = {{0,0,0,0},{0,0,0,0}};
    __syncthreads();

    // scores mapping: 16 n-vecs of 8, 4 rows, 8 s-slices of 16
    const int nv = tid & 15, srow = (tid >> 4) & 3, ssl = tid >> 6;
    const ushort_t* Dp0 = D + (long)(b0 + srow) * 16384 + (ssl * 16) * 128 + nv * 8;

    for (int t = 0; t < 128; ++t) {
        // ---- wq MFMA: 1 tile/wave (nt = w), K=512 over [h;c] ----
        {
            f32x4 acc = {0.f, 0.f, 0.f, 0.f};
            const ushort_t* af = WqeF + ((long)w * 64 + l) * 8;
            for (int kb = 0; kb < 16; ++kb) {
                const int ko = kb * 32 + kq * 8;
                const bf16x8 a  = ld_bf8(af + (long)kb * 4096);
                const bf16x8 bh = ld_bf8(&sd_hi[r_][ko]);
                const bf16x8 bl = ld_bf8(&sd_lo[r_][ko]);
                acc = MFMA_B16(a, bh, acc);
                acc = MFMA_B16(a, bl, acc);
            }
            if (r_ < 4) {
#pragma unroll
                for (int reg = 0; reg < 4; ++reg)
                    wqs[w * 16 + kq * 4 + reg][r_] = acc[reg];
            }
        }
        __syncthreads();
        // ---- attention scores (VALU, R4-verified) ----
        {
            float a[8];
#pragma unroll
            for (int j = 0; j < 8; ++j) a[j] = 0.0f;
#pragma unroll 4
            for (int s = 0; s < 16; ++s) {
                const int sg = ssl * 16 + s;
                const float wq = wqs[sg][srow];
                const float vv = ves[sg];
                const int4 wv = *(const int4*)(Dp0 + s * 128);
                float d[8];
                unp8(wv, d);
#pragma unroll
                for (int j = 0; j < 8; ++j)
                    a[j] = fmaf(tanh_fast(wq + d[j]), vv, a[j]);
            }
            *(float4*)&scp[ssl][srow][nv * 8]     = make_float4(a[0], a[1], a[2], a[3]);
            *(float4*)&scp[ssl][srow][nv * 8 + 4] = make_float4(a[4], a[5], a[6], a[7]);
        }
        __syncthreads();
        // ---- softmax + x_tilde -> sd x-region (hi/lo) ----
        if (tid < 256) {
            const int wv = tid >> 6, lane = tid & 63;
            float s0 = 0.0f, s1 = 0.0f;
#pragma unroll
            for (int g = 0; g < 8; ++g) {
                s0 += scp[g][wv][lane];
                s1 += scp[g][wv][lane + 64];
            }
            float mx = fmaxf(s0, s1);
            for (int o = 32; o > 0; o >>= 1) mx = fmaxf(mx, __shfl_xor(mx, o, 64));
            const float e0 = __expf(s0 - mx), e1 = __expf(s1 - mx);
            float sm = e0 + e1;
            for (int o = 32; o > 0; o >>= 1) sm += __shfl_xor(sm, o, 64);
            const float inv = __fdividef(1.0f, sm);
            const float* xp = enc_data + ((long)(b0 + wv) * 128 + t) * 128;
            const float x0 = e0 * inv * xp[lane];
            const float x1 = e1 * inv * xp[lane + 64];
            const ushort_t h0 = f2bf(x0), lo0 = f2bf(x0 - bf2f(h0));
            const ushort_t h1 = f2bf(x1), lo1 = f2bf(x1 - bf2f(h1));
            sd_hi[wv][512 + lane] = h0;      sd_lo[wv][512 + lane] = lo0;
            sd_hi[wv][512 + lane + 64] = h1; sd_lo[wv][512 + lane + 64] = lo1;
        }
        __syncthreads();
        // ---- gates MFMA: 8 tiles/wave, kb 0..3 = x region, 4..11 = h region ----
        f32x4 ga[8];
#pragma unroll
        for (int tt2 = 0; tt2 < 8; ++tt2) {
            const int q = tt2 >> 1, uh = tt2 & 1;
            const float4 b4 = *(const float4*)&ebsum[q * 256 + w * 32 + uh * 16 + kq * 4];
            ga[tt2][0] = b4.x; ga[tt2][1] = b4.y; ga[tt2][2] = b4.z; ga[tt2][3] = b4.w;
        }
        for (int kb = 0; kb < 12; ++kb) {
            const int ko = (kb < 4) ? (512 + kb * 32 + kq * 8) : ((kb - 4) * 32 + kq * 8);
            const bf16x8 bh = ld_bf8(&sd_hi[r_][ko]);
            const bf16x8 bl = ld_bf8(&sd_lo[r_][ko]);
            const ushort_t* gf = GeF + (((long)kb * 64 + w * 8) * 64 + l) * 8;
#pragma unroll
            for (int tt2 = 0; tt2 < 8; ++tt2) {
                const bf16x8 a = ld_bf8(gf + (long)tt2 * 512);
                ga[tt2] = MFMA_B16(a, bh, ga[tt2]);
                ga[tt2] = MFMA_B16(a, bl, ga[tt2]);
            }
        }
        __syncthreads();   // all sd reads done before epilogue writes
        // ---- LSTM epilogue (lanes with r_<4): cell in regs, h/c -> sd hi/lo ----
        if (r_ < 4) {
#pragma unroll
            for (int uh = 0; uh < 2; ++uh) {
                const int ub = w * 32 + uh * 16 + kq * 4;
                ushort_t dh[4], dl[4], ch[4], cl[4];
#pragma unroll
                for (int reg = 0; reg < 4; ++reg) {
                    const float iv = sig_fast(ga[uh][reg]);
                    const float fv = sig_fast(ga[2 + uh][reg]);
                    const float gv = tanh_fast(ga[4 + uh][reg]);
                    const float ov = sig_fast(ga[6 + uh][reg]);
                    const float cn = fv * cell[uh][reg] + iv * gv;
                    const float hn = ov * tanh_fast(cn);
                    cell[uh][reg] = cn;
                    dh[reg] = f2bf(hn); dl[reg] = f2bf(hn - bf2f(dh[reg]));
                    ch[reg] = f2bf(cn); cl[reg] = f2bf(cn - bf2f(ch[reg]));
                }
                *(ushort4*)&sd_hi[r_][ub]       = make_ushort4(dh[0], dh[1], dh[2], dh[3]);
                *(ushort4*)&sd_lo[r_][ub]       = make_ushort4(dl[0], dl[1], dl[2], dl[3]);
                *(ushort4*)&sd_hi[r_][256 + ub] = make_ushort4(ch[0], ch[1], ch[2], ch[3]);
                *(ushort4*)&sd_lo[r_][256 + ub] = make_ushort4(cl[0], cl[1], cl[2], cl[3]);
                *(ushort4*)&Hbf[((long)(b0 + r_) * 128 + t) * 256 + ub] =
                    make_ushort4(dh[0], dh[1], dh[2], dh[3]);
            }
        }
        __syncthreads();
    }
}

// ---------------------------------------------------------------------------
// Persistent decoder + final MLP: 256 blocks x 512 threads, 4 rows/block.
// ---------------------------------------------------------------------------
__global__ __launch_bounds__(512) void dec_persist(
    const float* __restrict__ dec_data,   // [1024][128]
    const ushort_t* __restrict__ UH2,     // [1024][256][128] bf16
    const ushort_t* __restrict__ Hb,      // [1024][128][256] bf16
    const ushort_t* __restrict__ WqdF,    // wq frags: 16kb x 16nt
    const ushort_t* __restrict__ GdF,     // gate frags: 8kb x 64nt
    const float* __restrict__ dbsum,      // [1024]
    const float* __restrict__ wy,         // [1024]  wy[u*4+q]
    const float* __restrict__ vd,         // [256]
    const float* __restrict__ wt_w, const float* __restrict__ wt_b,
    const float* __restrict__ l1T,        // [512][256]
    const float* __restrict__ l1_b,
    const float* __restrict__ l2_w, const float* __restrict__ l2_b,
    float* __restrict__ out)
{
    const int tid = threadIdx.x;
    const int b0 = blockIdx.x * 4;
    const int w = tid >> 6, l = tid & 63;
    const int r_ = l & 15, kq = l >> 4;
    __shared__ __align__(16) ushort_t sd_hi[16][DRW];
    __shared__ __align__(16) ushort_t sd_lo[16][DRW];
    __shared__ __align__(16) float wqs[256][4];
    __shared__ __align__(16) float scp[8][4][128];
    __shared__ __align__(16) float beta[128][4];
    __shared__ __align__(16) float ctxp[4][4][256];
    __shared__ __align__(16) float ctx4[256][4];
    __shared__ __align__(16) float dsf[256][4];
    __shared__ __align__(16) float o14[256][4];
    __shared__ float vds[256];
    __shared__ float wt1s[256];
    __shared__ float l2s[256];
    __shared__ __align__(16) float yts[4];

    if (tid < 256) {
        vds[tid] = vd[tid];
        wt1s[tid] = wt_w[1 + tid];
        l2s[tid] = l2_w[tid];
    }
    for (int i = tid; i < 16 * DRW / 2; i += 512) {
        ((unsigned int*)sd_hi)[i] = 0u;
        ((unsigned int*)sd_lo)[i] = 0u;
    }
    float cell[2][4] = {{0,0,0,0},{0,0,0,0}};
    __syncthreads();

    // scores mapping: 16 t'-vecs of 8, 4 rows, 8 u-slices of 32
    const int tv = tid & 15, srow = (tid >> 4) & 3, usl = tid >> 6;
    const ushort_t* up0 = UH2 + ((long)(b0 + srow) * 256 + usl * 32) * 128 + tv * 8;
    // ctx mapping: 32 m-vecs of 8, 4 rows, 4 s-slices of 32
    const int mv8 = tid & 31, crow = (tid >> 5) & 3, ssl2 = tid >> 7;
    const ushort_t* hp0 = Hb + ((long)(b0 + crow) * 128 + ssl2 * 32) * 256 + mv8 * 8;

    for (int td = 0; td < 128; ++td) {
        // ---- wq MFMA: 2 tiles/wave, K=512 over [d;s] ----
        {
            f32x4 acc0 = {0.f,0.f,0.f,0.f}, acc1 = {0.f,0.f,0.f,0.f};
            const int nt0 = w * 2;
            const ushort_t* af = WqdF + ((long)nt0 * 64 + l) * 8;
            for (int kb = 0; kb < 16; ++kb) {
                const int ko = kb * 32 + kq * 8;
                const bf16x8 bh = ld_bf8(&sd_hi[r_][ko]);
                const bf16x8 bl = ld_bf8(&sd_lo[r_][ko]);
                const ushort_t* p = af + (long)kb * 8192;
                const bf16x8 a0 = ld_bf8(p);
                const bf16x8 a1 = ld_bf8(p + 512);
                acc0 = MFMA_B16(a0, bh, acc0);
                acc0 = MFMA_B16(a0, bl, acc0);
                acc1 = MFMA_B16(a1, bh, acc1);
                acc1 = MFMA_B16(a1, bl, acc1);
            }
            if (r_ < 4) {
#pragma unroll
                for (int reg = 0; reg < 4; ++reg) {
                    wqs[nt0 * 16 + kq * 4 + reg][r_] = acc0[reg];
                    wqs[nt0 * 16 + 16 + kq * 4 + reg][r_] = acc1[reg];
                }
            }
        }
        __syncthreads();
        // ---- temporal scores (VALU, R4-verified) ----
        {
            float a[8];
#pragma unroll
            for (int j = 0; j < 8; ++j) a[j] = 0.0f;
#pragma unroll 4
            for (int uu = 0; uu < 32; ++uu) {
                const int ug = usl * 32 + uu;
                const float wq = wqs[ug][srow];
                const float vv = vds[ug];
                const int4 wv = *(const int4*)(up0 + uu * 128);
                float d[8];
                unp8(wv, d);
#pragma unroll
                for (int j = 0; j < 8; ++j)
                    a[j] = fmaf(tanh_fast(wq + d[j]), vv, a[j]);
            }
            *(float4*)&scp[usl][srow][tv * 8]     = make_float4(a[0], a[1], a[2], a[3]);
            *(float4*)&scp[usl][srow][tv * 8 + 4] = make_float4(a[4], a[5], a[6], a[7]);
        }
        __syncthreads();
        // ---- softmax -> beta ----
        if (tid < 256) {
            const int wv = tid >> 6, lane = tid & 63;
            float s0 = 0.0f, s1 = 0.0f;
#pragma unroll
            for (int g = 0; g < 8; ++g) {
                s0 += scp[g][wv][lane];
                s1 += scp[g][wv][lane + 64];
            }
            float mx = fmaxf(s0, s1);
            for (int o = 32; o > 0; o >>= 1) mx = fmaxf(mx, __shfl_xor(mx, o, 64));
            const float e0 = __expf(s0 - mx), e1 = __expf(s1 - mx);
            float sm = e0 + e1;
            for (int o = 32; o > 0; o >>= 1) sm += __shfl_xor(sm, o, 64);
            const float inv = __fdividef(1.0f, sm);
            beta[lane][wv] = e0 * inv;
            beta[lane + 64][wv] = e1 * inv;
        }
        __syncthreads();
        // ---- ctx partials (VALU) ----
        {
            float c[8];
#pragma unroll
            for (int j = 0; j < 8; ++j) c[j] = 0.0f;
#pragma unroll 4
            for (int s = 0; s < 32; ++s) {
                const float bt = beta[ssl2 * 32 + s][crow];
                const int4 wv = *(const int4*)(hp0 + s * 256);
                float hv[8];
                unp8(wv, hv);
#pragma unroll
                for (int j = 0; j < 8; ++j)
                    c[j] = fmaf(bt, hv[j], c[j]);
            }
            *(float4*)&ctxp[ssl2][crow][mv8 * 8]     = make_float4(c[0], c[1], c[2], c[3]);
            *(float4*)&ctxp[ssl2][crow][mv8 * 8 + 4] = make_float4(c[4], c[5], c[6], c[7]);
        }
        __syncthreads();
        // ---- ctx combine ----
        if (tid < 256) {
            const int m = tid;
            float cr[4];
#pragma unroll
            for (int r = 0; r < 4; ++r)
                cr[r] = ctxp[0][r][m] + ctxp[1][r][m] + ctxp[2][r][m] + ctxp[3][r][m];
            *(float4*)ctx4[m] = make_float4(cr[0], cr[1], cr[2], cr[3]);
        }
        __syncthreads();
        if (td == 127) break;     // final ctx computed with final (d,s)
        // ---- y_tilde (waves 0-3) + gates MFMA (all waves) ----
        if (tid < 256) {
            const int wv = tid >> 6, lane = tid & 63;
            float s = ctx4[lane][wv] * wt1s[lane]
                    + ctx4[lane + 64][wv] * wt1s[lane + 64]
                    + ctx4[lane + 128][wv] * wt1s[lane + 128]
                    + ctx4[lane + 192][wv] * wt1s[lane + 192];
            for (int o = 32; o > 0; o >>= 1) s += __shfl_xor(s, o, 64);
            if (lane == 0)
                yts[wv] = s + wt_b[0] + wt_w[0] * dec_data[(long)(b0 + wv) * 128 + td];
        }
        f32x4 ga[8];
#pragma unroll
        for (int tt2 = 0; tt2 < 8; ++tt2) {
            const int q = tt2 >> 1, uh = tt2 & 1;
            const float4 b4 = *(const float4*)&dbsum[q * 256 + w * 32 + uh * 16 + kq * 4];
            ga[tt2][0] = b4.x; ga[tt2][1] = b4.y; ga[tt2][2] = b4.z; ga[tt2][3] = b4.w;
        }
        for (int kb = 0; kb < 8; ++kb) {
            const int ko = kb * 32 + kq * 8;     // d region
            const bf16x8 bh = ld_bf8(&sd_hi[r_][ko]);
            const bf16x8 bl = ld_bf8(&sd_lo[r_][ko]);
            const ushort_t* gf = GdF + (((long)kb * 64 + w * 8) * 64 + l) * 8;
#pragma unroll
            for (int tt2 = 0; tt2 < 8; ++tt2) {
                const bf16x8 a = ld_bf8(gf + (long)tt2 * 512);
                ga[tt2] = MFMA_B16(a, bh, ga[tt2]);
                ga[tt2] = MFMA_B16(a, bl, ga[tt2]);
            }
        }
        __syncthreads();   // sd reads + yts writes complete
        // ---- LSTM epilogue ----
        if (r_ < 4) {
            const float yr = yts[r_];
#pragma unroll
            for (int uh = 0; uh < 2; ++uh) {
                const int ub = w * 32 + uh * 16 + kq * 4;
                ushort_t dh[4], dl[4], sh[4], sl[4];
#pragma unroll
                for (int reg = 0; reg < 4; ++reg) {
                    const int u = ub + reg;
                    const float4 wy4 = *(const float4*)&wy[u * 4];
                    const float iv = sig_fast(ga[uh][reg] + wy4.x * yr);
                    const float fv = sig_fast(ga[2 + uh][reg] + wy4.y * yr);
                    const float gv = tanh_fast(ga[4 + uh][reg] + wy4.z * yr);
                    const float ov = sig_fast(ga[6 + uh][reg] + wy4.w * yr);
                    const float sn = fv * cell[uh][reg] + iv * gv;
                    const float dn = ov * tanh_fast(sn);
                    cell[uh][reg] = sn;
                    dh[reg] = f2bf(dn); dl[reg] = f2bf(dn - bf2f(dh[reg]));
                    sh[reg] = f2bf(sn); sl[reg] = f2bf(sn - bf2f(sh[reg]));
                    if (td == 126) dsf[u][r_] = dn;
                }
                *(ushort4*)&sd_hi[r_][ub]       = make_ushort4(dh[0], dh[1], dh[2], dh[3]);
                *(ushort4*)&sd_lo[r_][ub]       = make_ushort4(dl[0], dl[1], dl[2], dl[3]);
                *(ushort4*)&sd_hi[r_][256 + ub] = make_ushort4(sh[0], sh[1], sh[2], sh[3]);
                *(ushort4*)&sd_lo[r_][256 + ub] = make_ushort4(sl[0], sl[1], sl[2], sl[3]);
            }
        }
        __syncthreads();
    }
    // ---- final MLP: l1 (k-split 2 via scp scratch), relu, l2 reduce ----
    {
        float* scr = &scp[0][0][0];               // reuse as [2][4][256]
        const int ks = tid >> 8, u = tid & 255;
        const float* src = l1T + (long)ks * 256 * 256;
        float a0 = 0, a1 = 0, a2 = 0, a3 = 0;
#pragma unroll 4
        for (int k = 0; k < 256; ++k) {
            const float wv = src[k * 256 + u];
            const float4 q = (ks == 0) ? *(const float4*)dsf[k]
                                       : *(const float4*)ctx4[k];
            a0 = fmaf(q.x, wv, a0); a1 = fmaf(q.y, wv, a1);
            a2 = fmaf(q.z, wv, a2); a3 = fmaf(q.w, wv, a3);
        }
        scr[(ks * 4 + 0) * 256 + u] = a0;
        scr[(ks * 4 + 1) * 256 + u] = a1;
        scr[(ks * 4 + 2) * 256 + u] = a2;
        scr[(ks * 4 + 3) * 256 + u] = a3;
    }
    __syncthreads();
    if (tid < 256) {
        const float* scr = &scp[0][0][0];
        const float bb = l1_b[tid];
        *(float4*)o14[tid] = make_float4(
            fmaxf(scr[0 * 256 + tid] + scr[4 * 256 + tid] + bb, 0.f),
            fmaxf(scr[1 * 256 + tid] + scr[5 * 256 + tid] + bb, 0.f),
            fmaxf(scr[2 * 256 + tid] + scr[6 * 256 + tid] + bb, 0.f),
            fmaxf(scr[3 * 256 + tid] + scr[7 * 256 + tid] + bb, 0.f));
    }
    __syncthreads();
    if (tid < 256) {
        const int wv = tid >> 6, lane = tid & 63;
        float s = o14[lane][wv] * l2s[lane]
                + o14[lane + 64][wv] * l2s[lane + 64]
                + o14[lane + 128][wv] * l2s[lane + 128]
                + o14[lane + 192][wv] * l2s[lane + 192];
        for (int o = 32; o > 0; o >>= 1) s += __shfl_xor(s, o, 64);
        if (lane == 0) out[b0 + wv] = s + l2_b[0];
    }
}

extern "C" void kernel_launch(void* const* d_in, const int* in_sizes, int n_in,
                              void* d_out, int out_size, void* d_ws, size_t ws_size,
                              hipStream_t stream)
{
    const float* enc_data = (const float*)d_in[0];
    const float* dec_data = (const float*)d_in[1];
    const float* enc_Wih  = (const float*)d_in[2];
    const float* enc_Whh  = (const float*)d_in[3];
    const float* enc_bih  = (const float*)d_in[4];
    const float* enc_bhh  = (const float*)d_in[5];
    const float* We   = (const float*)d_in[6];
    const float* Ue   = (const float*)d_in[7];
    const float* ve   = (const float*)d_in[8];
    const float* Wd   = (const float*)d_in[9];
    const float* Ud   = (const float*)d_in[10];
    const float* vd   = (const float*)d_in[11];
    const float* wt_w = (const float*)d_in[12];
    const float* wt_b = (const float*)d_in[13];
    const float* dec_Wih = (const float*)d_in[14];
    const float* dec_Whh = (const float*)d_in[15];
    const float* dec_bih = (const float*)d_in[16];
    const float* dec_bhh = (const float*)d_in[17];
    const float* l1_w = (const float*)d_in[18];
    const float* l1_b = (const float*)d_in[19];
    const float* l2_w = (const float*)d_in[20];
    const float* l2_b = (const float*)d_in[21];

    // ---- workspace layout (~162 MB) ----
    ushort_t* Dbf  = (ushort_t*)d_ws;                         // 1024*128*128
    ushort_t* Hbf  = Dbf + (long)BATCH * TT * NN;             // 1024*128*256
    ushort_t* UHbf = Hbf + (long)BATCH * TT * MM;             // 1024*256*128
    ushort_t* WqeF = UHbf + (long)BATCH * MM * TT;            // 512*128
    ushort_t* WqdF = WqeF + 512 * 128;                        // 512*256
    ushort_t* GeF  = WqdF + 512 * 256;                        // 384*1024
    ushort_t* GdF  = GeF + 384 * 1024;                        // 256*1024
    float* fbase = (float*)(GdF + 256 * 1024);
    float* ebsum = fbase;                                     // 1024
    float* dbsum = ebsum + 1024;                              // 1024
    float* wy    = dbsum + 1024;                              // 1024
    float* l1T   = wy + 1024;                                 // 512*256

    // ---- weight prep ----
    pack_frag_k<<<(512 * 8 * 16 + 255) / 256, 256, 0, stream>>>(
        We, 512, 512, nullptr, 0, 512, 8, 0, WqeF);
    pack_frag_k<<<(512 * 16 * 16 + 255) / 256, 256, 0, stream>>>(
        Wd, 512, 512, nullptr, 0, 512, 16, 0, WqdF);
    pack_frag_k<<<(384 * 64 * 16 + 255) / 256, 256, 0, stream>>>(
        enc_Wih, 128, 128, enc_Whh, 256, 384, 64, 1, GeF);
    pack_frag_k<<<(256 * 64 * 16 + 255) / 256, 256, 0, stream>>>(
        dec_Whh, 256, 256, nullptr, 0, 256, 64, 1, GdF);
    prep_misc_k<<<4, 256, 0, stream>>>(enc_bih, enc_bhh, dec_bih, dec_bhh,
                                       dec_Wih, ebsum, dbsum, wy);
    transpose_k<<<(256 * 512 + 255) / 256, 256, 0, stream>>>(l1_w, l1T, 256, 512);

    // D[b][s][n] = sum_t Ue[s][t] * enc_data[b][t][n]
    gemm_k<false, true, true, false><<<dim3(NN / 64, TT / 64, BATCH), 256, 0, stream>>>(
        Ue, TT, 0, TT,
        nullptr, 0, 0,
        enc_data, NN, (long)TT * NN,
        nullptr, 0,
        nullptr,
        Dbf, NN, (long)TT * NN);

    enc_persist<<<256, 512, 0, stream>>>(enc_data, Dbf, WqeF, GeF, ebsum, ve, Hbf);

    // UH2[b][u][t'] = sum_m Ud[u][m] * H[b][t'][m]
    gemm_k<true, false, true, false><<<dim3(TT / 64, MM / 64, BATCH), 256, 0, stream>>>(
        Ud, MM, 0, MM,
        nullptr, 0, 0,
        Hbf, MM, (long)TT * MM,
        nullptr, 0,
        nullptr,
        UHbf, TT, (long)MM * TT);

    dec_persist<<<256, 512, 0, stream>>>(dec_data, UHbf, Hbf, WqdF, GdF,
                                         dbsum, wy, vd, wt_w, wt_b,
                                         l1T, l1_b, l2_w, l2_b, (float*)d_out);
}

// Round 7
// 15493.245 us; speedup vs baseline: 1.0070x; 1.0070x over previous
//
#include <hip/hip_runtime.h>

typedef unsigned short ushort_t;
typedef __attribute__((ext_vector_type(8))) __bf16 bf16x8;
typedef __attribute__((ext_vector_type(4))) float f32x4;

#define MFMA_B16(a,b,c) __builtin_amdgcn_mfma_f32_16x16x32_bf16(a,b,c,0,0,0)

static constexpr int BATCH = 1024;
static constexpr int TT = 128;   // T
static constexpr int NN = 128;   // N
static constexpr int MM = 256;   // M == P
static constexpr int ERW = 648;  // enc state row width (ushorts): h256|c256|x128|pad8
static constexpr int DRW = 520;  // dec state row width: d256|s256|pad8

__device__ __forceinline__ float bf2f(ushort_t u) {
    union { unsigned int i; float f; } v;
    v.i = ((unsigned int)u) << 16;
    return v.f;
}
__device__ __forceinline__ ushort_t f2bf(float f) {
    union { unsigned int i; float f; } v;
    v.f = f;
    unsigned int i = v.i;
    return (ushort_t)((i + 0x7FFFu + ((i >> 16) & 1u)) >> 16);
}
// 16B-aligned load of 8 bf16 as MFMA operand
__device__ __forceinline__ bf16x8 ld_bf8(const ushort_t* p) {
    return __builtin_bit_cast(bf16x8, *(const int4*)p);
}
__device__ __forceinline__ void unp8(const int4 w, float* o) {
    union { unsigned int i; float f; } v;
    v.i = ((unsigned int)w.x) << 16;         o[0] = v.f;
    v.i = ((unsigned int)w.x) & 0xffff0000u; o[1] = v.f;
    v.i = ((unsigned int)w.y) << 16;         o[2] = v.f;
    v.i = ((unsigned int)w.y) & 0xffff0000u; o[3] = v.f;
    v.i = ((unsigned int)w.z) << 16;         o[4] = v.f;
    v.i = ((unsigned int)w.z) & 0xffff0000u; o[5] = v.f;
    v.i = ((unsigned int)w.w) << 16;         o[6] = v.f;
    v.i = ((unsigned int)w.w) & 0xffff0000u; o[7] = v.f;
}
// inf-safe without clamps: __fdividef(2,inf)=0, exp underflow->0
__device__ __forceinline__ float tanh_fast(float x) {
    float e = __expf(2.0f * x);
    return 1.0f - __fdividef(2.0f, e + 1.0f);
}
__device__ __forceinline__ float sig_fast(float x) {
    return __fdividef(1.0f, 1.0f + __expf(-x));
}

// ---------------------------------------------------------------------------
// Generic tiled GEMM (verified R1) — only for the two one-time precomputes.
// ---------------------------------------------------------------------------
template<bool WBF16, bool TRANSW, bool CBF16, bool RELU>
__global__ __launch_bounds__(256) void gemm_k(
    const float* __restrict__ A1, int lda1, long sA1z, int K1,
    const float* __restrict__ A2, int lda2, int K2,
    const void* __restrict__ W1v, int ldw1, long sW1z,
    const void* __restrict__ W2v, int ldw2,
    const float* __restrict__ bias1,
    void* __restrict__ Cv, int ldc, long sCz)
{
    __shared__ float As[32][68];
    __shared__ float Ws[32][68];
    const int tid = threadIdx.x;
    const int z = blockIdx.z;
    const int m0 = blockIdx.y * 64;
    const int g0 = blockIdx.x * 64;
    const int tm = tid & 15, tn = tid >> 4;
    float acc[4][4];
#pragma unroll
    for (int i = 0; i < 4; ++i)
#pragma unroll
        for (int j = 0; j < 4; ++j) acc[i][j] = 0.0f;

    for (int phase = 0; phase < 2; ++phase) {
        const float* A = (phase == 0) ? (A1 + (long)z * sA1z) : A2;
        const int lda = (phase == 0) ? lda1 : lda2;
        const int K = (phase == 0) ? K1 : K2;
        const int ldw = (phase == 0) ? ldw1 : ldw2;
        const void* Wv = (phase == 0) ? W1v : W2v;
        const long woff = (phase == 0) ? (long)z * sW1z : 0;
        if (A == nullptr || Wv == nullptr || K <= 0) continue;

        for (int k0 = 0; k0 < K; k0 += 32) {
            const int rem = K - k0;
            {
                const int tr0 = tid >> 3;
                const int tk = (tid & 7) * 4;
#pragma unroll
                for (int pass = 0; pass < 2; ++pass) {
                    const int m = tr0 + pass * 32;
                    const float* p = A + (long)(m0 + m) * lda + k0 + tk;
#pragma unroll
                    for (int j = 0; j < 4; ++j) {
                        float v = 0.0f;
                        if (tk + j < rem) v = p[j];
                        As[tk + j][m] = v;
                    }
                }
            }
            if constexpr (TRANSW) {
                const float* W = (const float*)Wv + woff;
                const int gq = (tid & 15) * 4;
                const int kr = tid >> 4;
#pragma unroll
                for (int pass = 0; pass < 2; ++pass) {
                    const int k = kr + pass * 16;
                    const float* p = W + (long)(k0 + k) * ldw + g0 + gq;
                    const bool ok = (k < rem);
#pragma unroll
                    for (int j = 0; j < 4; ++j) {
                        float v = 0.0f;
                        if (ok) v = p[j];
                        Ws[k][gq + j] = v;
                    }
                }
            } else if constexpr (WBF16) {
                const ushort_t* W = (const ushort_t*)Wv + woff;
                const int g = tid >> 2;
                const int tk = (tid & 3) * 8;
                const ushort_t* p = W + (long)(g0 + g) * ldw + k0 + tk;
#pragma unroll
                for (int j = 0; j < 8; ++j) {
                    float v = 0.0f;
                    if (tk + j < rem) v = bf2f(p[j]);
                    Ws[tk + j][g] = v;
                }
            } else {
                const float* W = (const float*)Wv + woff;
                const int tr0 = tid >> 3;
                const int tk = (tid & 7) * 4;
#pragma unroll
                for (int pass = 0; pass < 2; ++pass) {
                    const int g = tr0 + pass * 32;
                    const float* p = W + (long)(g0 + g) * ldw + k0 + tk;
#pragma unroll
                    for (int j = 0; j < 4; ++j) {
                        float v = 0.0f;
                        if (tk + j < rem) v = p[j];
                        Ws[tk + j][g] = v;
                    }
                }
            }
            __syncthreads();
#pragma unroll
            for (int kk = 0; kk < 32; ++kk) {
                const float4 av = *(const float4*)&As[kk][tm * 4];
                const float4 bv = *(const float4*)&Ws[kk][tn * 4];
                const float a[4] = {av.x, av.y, av.z, av.w};
                const float b[4] = {bv.x, bv.y, bv.z, bv.w};
#pragma unroll
                for (int i = 0; i < 4; ++i)
#pragma unroll
                    for (int j = 0; j < 4; ++j)
                        acc[i][j] = fmaf(a[i], b[j], acc[i][j]);
            }
            __syncthreads();
        }
    }
#pragma unroll
    for (int i = 0; i < 4; ++i) {
        const long m = m0 + tm * 4 + i;
#pragma unroll
        for (int j = 0; j < 4; ++j) {
            const int g = g0 + tn * 4 + j;
            float v = acc[i][j];
            if (bias1) v += bias1[g];
            if (RELU) v = fmaxf(v, 0.0f);
            if constexpr (CBF16)
                ((ushort_t*)Cv)[(long)z * sCz + m * ldc + g] = f2bf(v);
            else
                ((float*)Cv)[(long)z * sCz + m * ldc + g] = v;
        }
    }
}

// ---------------------------------------------------------------------------
// Pack fp32 weights into bf16 MFMA A-operand fragments.
// frag[((kb*NT + nt)*64 + l)*8 + j] = W[g][k], k = kb*32+(l>>4)*8+j,
// g = mode ? gatemap(nt, l&15) : nt*16 + (l&15).
// ---------------------------------------------------------------------------
__global__ void pack_frag_k(const float* __restrict__ W1, int ld1, int K1,
                            const float* __restrict__ W2, int ld2,
                            int Ktot, int NT, int mode,
                            ushort_t* __restrict__ dst)
{
    const int idx = blockIdx.x * 256 + threadIdx.x;
    const int total = Ktot * NT * 16;
    if (idx >= total) return;
    const int j = idx & 7, l = (idx >> 3) & 63, rest = idx >> 9;
    const int nt = rest % NT, kb = rest / NT;
    const int c = l & 15;
    const int k = kb * 32 + (l >> 4) * 8 + j;
    int g;
    if (mode) {
        const int w = nt >> 3, tt = nt & 7, q = tt >> 1, uh = tt & 1;
        g = q * 256 + w * 32 + uh * 16 + c;
    } else {
        g = nt * 16 + c;
    }
    const float v = (k < K1) ? W1[(long)g * ld1 + k] : W2[(long)g * ld2 + (k - K1)];
    dst[idx] = f2bf(v);
}

__global__ void prep_misc_k(const float* __restrict__ ebih, const float* __restrict__ ebhh,
                            const float* __restrict__ dbih, const float* __restrict__ dbhh,
                            const float* __restrict__ dWih,
                            float* __restrict__ ebsum, float* __restrict__ dbsum,
                            float* __restrict__ wy)
{
    const int i = blockIdx.x * 256 + threadIdx.x;
    if (i < 1024) {
        ebsum[i] = ebih[i] + ebhh[i];
        dbsum[i] = dbih[i] + dbhh[i];
        const int q = i & 3, u = i >> 2;
        wy[i] = dWih[q * 256 + u];
    }
}

__global__ void transpose_k(const float* __restrict__ src, float* __restrict__ dst,
                            int R, int C) {
    int i = blockIdx.x * 256 + threadIdx.x;
    if (i < R * C) { int r = i / C, c = i - r * C; dst[c * R + r] = src[i]; }
}

// ---------------------------------------------------------------------------
// Persistent encoder: 256 blocks x 512 threads, 4 rows/block.
// __launch_bounds__(512,2): 1 block/CU (LDS-bound anyway) -> 256 VGPRs, no spill.
// ---------------------------------------------------------------------------
__global__ __launch_bounds__(512, 2) void enc_persist(
    const float* __restrict__ enc_data,   // [1024][128][128]
    const ushort_t* __restrict__ D,       // [1024][128][128] bf16
    const ushort_t* __restrict__ WqeF,    // wq frags: 16kb x 8nt
    const ushort_t* __restrict__ GeF,     // gate frags: 12kb x 64nt
    const float* __restrict__ ebsum,      // [1024]
    const float* __restrict__ ve,         // [128]
    ushort_t* __restrict__ Hbf)           // [1024][128][256] bf16
{
    const int tid = threadIdx.x;
    const int b0 = blockIdx.x * 4;
    const int w = tid >> 6, l = tid & 63;
    const int r_ = l & 15, kq = l >> 4;
    __shared__ __align__(16) ushort_t sd_hi[16][ERW];
    __shared__ __align__(16) ushort_t sd_lo[16][ERW];
    __shared__ __align__(16) float wqs[128][4];
    __shared__ __align__(16) float scp[8][4][128];
    __shared__ float ves[128];

    if (tid < 128) ves[tid] = ve[tid];
    for (int i = tid; i < 16 * ERW / 2; i += 512) {
        ((unsigned int*)sd_hi)[i] = 0u;
        ((unsigned int*)sd_lo)[i] = 0u;
    }
    float cell[2][4] = {{0,0,0,0},{0,0,0,0}};
    __syncthreads();

    // scores mapping: 16 n-vecs of 8, 4 rows, 8 s-slices of 16
    const int nv = tid & 15, srow = (tid >> 4) & 3, ssl = tid >> 6;
    const ushort_t* Dp0 = D + (long)(b0 + srow) * 16384 + (ssl * 16) * 128 + nv * 8;

    for (int t = 0; t < 128; ++t) {
        // ---- wq MFMA: 1 tile/wave (nt = w), K=512 over [h;c] ----
        {
            f32x4 acc = {0.f, 0.f, 0.f, 0.f};
            const ushort_t* af = WqeF + ((long)w * 64 + l) * 8;
            for (int kb = 0; kb < 16; ++kb) {
                const int ko = kb * 32 + kq * 8;
                const bf16x8 a  = ld_bf8(af + (long)kb * 4096);
                const bf16x8 bh = ld_bf8(&sd_hi[r_][ko]);
                const bf16x8 bl = ld_bf8(&sd_lo[r_][ko]);
                acc = MFMA_B16(a, bh, acc);
                acc = MFMA_B16(a, bl, acc);
            }
            if (r_ < 4) {
#pragma unroll
                for (int reg = 0; reg < 4; ++reg)
                    wqs[w * 16 + kq * 4 + reg][r_] = acc[reg];
            }
        }
        __syncthreads();
        // ---- attention scores (VALU, R4-verified) ----
        {
            float a[8];
#pragma unroll
            for (int j = 0; j < 8; ++j) a[j] = 0.0f;
#pragma unroll 4
            for (int s = 0; s < 16; ++s) {
                const int sg = ssl * 16 + s;
                const float wq = wqs[sg][srow];
                const float vv = ves[sg];
                const int4 wv = *(const int4*)(Dp0 + s * 128);
                float d[8];
                unp8(wv, d);
#pragma unroll
                for (int j = 0; j < 8; ++j)
                    a[j] = fmaf(tanh_fast(wq + d[j]), vv, a[j]);
            }
            *(float4*)&scp[ssl][srow][nv * 8]     = make_float4(a[0], a[1], a[2], a[3]);
            *(float4*)&scp[ssl][srow][nv * 8 + 4] = make_float4(a[4], a[5], a[6], a[7]);
        }
        __syncthreads();
        // ---- softmax + x_tilde -> sd x-region (hi/lo) ----
        if (tid < 256) {
            const int wv = tid >> 6, lane = tid & 63;
            float s0 = 0.0f, s1 = 0.0f;
#pragma unroll
            for (int g = 0; g < 8; ++g) {
                s0 += scp[g][wv][lane];
                s1 += scp[g][wv][lane + 64];
            }
            float mx = fmaxf(s0, s1);
            for (int o = 32; o > 0; o >>= 1) mx = fmaxf(mx, __shfl_xor(mx, o, 64));
            const float e0 = __expf(s0 - mx), e1 = __expf(s1 - mx);
            float sm = e0 + e1;
            for (int o = 32; o > 0; o >>= 1) sm += __shfl_xor(sm, o, 64);
            const float inv = __fdividef(1.0f, sm);
            const float* xp = enc_data + ((long)(b0 + wv) * 128 + t) * 128;
            const float x0 = e0 * inv * xp[lane];
            const float x1 = e1 * inv * xp[lane + 64];
            const ushort_t h0 = f2bf(x0), lo0 = f2bf(x0 - bf2f(h0));
            const ushort_t h1 = f2bf(x1), lo1 = f2bf(x1 - bf2f(h1));
            sd_hi[wv][512 + lane] = h0;      sd_lo[wv][512 + lane] = lo0;
            sd_hi[wv][512 + lane + 64] = h1; sd_lo[wv][512 + lane + 64] = lo1;
        }
        __syncthreads();
        // ---- gates MFMA: 8 tiles/wave, kb 0..3 = x region, 4..11 = h region ----
        f32x4 ga[8];
#pragma unroll
        for (int tt2 = 0; tt2 < 8; ++tt2) {
            const int q = tt2 >> 1, uh = tt2 & 1;
            const float4 b4 = *(const float4*)&ebsum[q * 256 + w * 32 + uh * 16 + kq * 4];
            ga[tt2][0] = b4.x; ga[tt2][1] = b4.y; ga[tt2][2] = b4.z; ga[tt2][3] = b4.w;
        }
        for (int kb = 0; kb < 12; ++kb) {
            const int ko = (kb < 4) ? (512 + kb * 32 + kq * 8) : ((kb - 4) * 32 + kq * 8);
            const bf16x8 bh = ld_bf8(&sd_hi[r_][ko]);
            const bf16x8 bl = ld_bf8(&sd_lo[r_][ko]);
            const ushort_t* gf = GeF + (((long)kb * 64 + w * 8) * 64 + l) * 8;
#pragma unroll
            for (int tt2 = 0; tt2 < 8; ++tt2) {
                const bf16x8 a = ld_bf8(gf + (long)tt2 * 512);
                ga[tt2] = MFMA_B16(a, bh, ga[tt2]);
                ga[tt2] = MFMA_B16(a, bl, ga[tt2]);
            }
        }
        __syncthreads();   // all sd reads done before epilogue writes
        // ---- LSTM epilogue (lanes with r_<4): cell in regs, h/c -> sd hi/lo ----
        if (r_ < 4) {
#pragma unroll
            for (int uh = 0; uh < 2; ++uh) {
                const int ub = w * 32 + uh * 16 + kq * 4;
                ushort_t dh[4], dl[4], ch[4], cl[4];
#pragma unroll
                for (int reg = 0; reg < 4; ++reg) {
                    const float iv = sig_fast(ga[uh][reg]);
                    const float fv = sig_fast(ga[2 + uh][reg]);
                    const float gv = tanh_fast(ga[4 + uh][reg]);
                    const float ov = sig_fast(ga[6 + uh][reg]);
                    const float cn = fv * cell[uh][reg] + iv * gv;
                    const float hn = ov * tanh_fast(cn);
                    cell[uh][reg] = cn;
                    dh[reg] = f2bf(hn); dl[reg] = f2bf(hn - bf2f(dh[reg]));
                    ch[reg] = f2bf(cn); cl[reg] = f2bf(cn - bf2f(ch[reg]));
                }
                *(ushort4*)&sd_hi[r_][ub]       = make_ushort4(dh[0], dh[1], dh[2], dh[3]);
                *(ushort4*)&sd_lo[r_][ub]       = make_ushort4(dl[0], dl[1], dl[2], dl[3]);
                *(ushort4*)&sd_hi[r_][256 + ub] = make_ushort4(ch[0], ch[1], ch[2], ch[3]);
                *(ushort4*)&sd_lo[r_][256 + ub] = make_ushort4(cl[0], cl[1], cl[2], cl[3]);
                *(ushort4*)&Hbf[((long)(b0 + r_) * 128 + t) * 256 + ub] =
                    make_ushort4(dh[0], dh[1], dh[2], dh[3]);
            }
        }
        __syncthreads();
    }
}

// ---------------------------------------------------------------------------
// Persistent decoder + final MLP: 256 blocks x 512 threads, 4 rows/block.
// ---------------------------------------------------------------------------
__global__ __launch_bounds__(512, 2) void dec_persist(
    const float* __restrict__ dec_data,   // [1024][128]
    const ushort_t* __restrict__ UH2,     // [1024][256][128] bf16
    const ushort_t* __restrict__ Hb,      // [1024][128][256] bf16
    const ushort_t* __restrict__ WqdF,    // wq frags: 16kb x 16nt
    const ushort_t* __restrict__ GdF,     // gate frags: 8kb x 64nt
    const float* __restrict__ dbsum,      // [1024]
    const float* __restrict__ wy,         // [1024]  wy[u*4+q]
    const float* __restrict__ vd,         // [256]
    const float* __restrict__ wt_w, const float* __restrict__ wt_b,
    const float* __restrict__ l1T,        // [512][256]
    const float* __restrict__ l1_b,
    const float* __restrict__ l2_w, const float* __restrict__ l2_b,
    float* __restrict__ out)
{
    const int tid = threadIdx.x;
    const int b0 = blockIdx.x * 4;
    const int w = tid >> 6, l = tid & 63;
    const int r_ = l & 15, kq = l >> 4;
    __shared__ __align__(16) ushort_t sd_hi[16][DRW];
    __shared__ __align__(16) ushort_t sd_lo[16][DRW];
    __shared__ __align__(16) float wqs[256][4];
    __shared__ __align__(16) float scp[8][4][128];
    __shared__ __align__(16) float beta[128][4];
    __shared__ __align__(16) float ctxp[4][4][256];
    __shared__ __align__(16) float ctx4[256][4];
    __shared__ __align__(16) float dsf[256][4];
    __shared__ __align__(16) float o14[256][4];
    __shared__ float vds[256];
    __shared__ float wt1s[256];
    __shared__ float l2s[256];
    __shared__ __align__(16) float yts[4];

    if (tid < 256) {
        vds[tid] = vd[tid];
        wt1s[tid] = wt_w[1 + tid];
        l2s[tid] = l2_w[tid];
    }
    for (int i = tid; i < 16 * DRW / 2; i += 512) {
        ((unsigned int*)sd_hi)[i] = 0u;
        ((unsigned int*)sd_lo)[i] = 0u;
    }
    float cell[2][4] = {{0,0,0,0},{0,0,0,0}};
    __syncthreads();

    // scores mapping: 16 t'-vecs of 8, 4 rows, 8 u-slices of 32
    const int tv = tid & 15, srow = (tid >> 4) & 3, usl = tid >> 6;
    const ushort_t* up0 = UH2 + ((long)(b0 + srow) * 256 + usl * 32) * 128 + tv * 8;
    // ctx mapping: 32 m-vecs of 8, 4 rows, 4 s-slices of 32
    const int mv8 = tid & 31, crow = (tid >> 5) & 3, ssl2 = tid >> 7;
    const ushort_t* hp0 = Hb + ((long)(b0 + crow) * 128 + ssl2 * 32) * 256 + mv8 * 8;

    for (int td = 0; td < 128; ++td) {
        // ---- wq MFMA: 2 tiles/wave, K=512 over [d;s] ----
        {
            f32x4 acc0 = {0.f,0.f,0.f,0.f}, acc1 = {0.f,0.f,0.f,0.f};
            const int nt0 = w * 2;
            const ushort_t* af = WqdF + ((long)nt0 * 64 + l) * 8;
            for (int kb = 0; kb < 16; ++kb) {
                const int ko = kb * 32 + kq * 8;
                const bf16x8 bh = ld_bf8(&sd_hi[r_][ko]);
                const bf16x8 bl = ld_bf8(&sd_lo[r_][ko]);
                const ushort_t* p = af + (long)kb * 8192;
                const bf16x8 a0 = ld_bf8(p);
                const bf16x8 a1 = ld_bf8(p + 512);
                acc0 = MFMA_B16(a0, bh, acc0);
                acc0 = MFMA_B16(a0, bl, acc0);
                acc1 = MFMA_B16(a1, bh, acc1);
                acc1 = MFMA_B16(a1, bl, acc1);
            }
            if (r_ < 4) {
#pragma unroll
                for (int reg = 0; reg < 4; ++reg) {
                    wqs[nt0 * 16 + kq * 4 + reg][r_] = acc0[reg];
                    wqs[nt0 * 16 + 16 + kq * 4 + reg][r_] = acc1[reg];
                }
            }
        }
        __syncthreads();
        // ---- temporal scores (VALU, R4-verified) ----
        {
            float a[8];
#pragma unroll
            for (int j = 0; j < 8; ++j) a[j] = 0.0f;
#pragma unroll 4
            for (int uu = 0; uu < 32; ++uu) {
                const int ug = usl * 32 + uu;
                const float wq = wqs[ug][srow];
                const float vv = vds[ug];
                const int4 wv = *(const int4*)(up0 + uu * 128);
                float d[8];
                unp8(wv, d);
#pragma unroll
                for (int j = 0; j < 8; ++j)
                    a[j] = fmaf(tanh_fast(wq + d[j]), vv, a[j]);
            }
            *(float4*)&scp[usl][srow][tv * 8]     = make_float4(a[0], a[1], a[2], a[3]);
            *(float4*)&scp[usl][srow][tv * 8 + 4] = make_float4(a[4], a[5], a[6], a[7]);
        }
        __syncthreads();
        // ---- softmax -> beta ----
        if (tid < 256) {
            const int wv = tid >> 6, lane = tid & 63;
            float s0 = 0.0f, s1 = 0.0f;
#pragma unroll
            for (int g = 0; g < 8; ++g) {
                s0 += scp[g][wv][lane];
                s1 += scp[g][wv][lane + 64];
            }
            float mx = fmaxf(s0, s1);
            for (int o = 32; o > 0; o >>= 1) mx = fmaxf(mx, __shfl_xor(mx, o, 64));
            const float e0 = __expf(s0 - mx), e1 = __expf(s1 - mx);
            float sm = e0 + e1;
            for (int o = 32; o > 0; o >>= 1) sm += __shfl_xor(sm, o, 64);
            const float inv = __fdividef(1.0f, sm);
            beta[lane][wv] = e0 * inv;
            beta[lane + 64][wv] = e1 * inv;
        }
        __syncthreads();
        // ---- ctx partials (VALU) ----
        {
            float c[8];
#pragma unroll
            for (int j = 0; j < 8; ++j) c[j] = 0.0f;
#pragma unroll 4
            for (int s = 0; s < 32; ++s) {
                const float bt = beta[ssl2 * 32 + s][crow];
                const int4 wv = *(const int4*)(hp0 + s * 256);
                float hv[8];
                unp8(wv, hv);
#pragma unroll
                for (int j = 0; j < 8; ++j)
                    c[j] = fmaf(bt, hv[j], c[j]);
            }
            *(float4*)&ctxp[ssl2][crow][mv8 * 8]     = make_float4(c[0], c[1], c[2], c[3]);
            *(float4*)&ctxp[ssl2][crow][mv8 * 8 + 4] = make_float4(c[4], c[5], c[6], c[7]);
        }
        __syncthreads();
        if (td == 127) break;     // final ctx combined after the loop
        // ---- y_tilde (waves 0-3, reads ctxp directly) + gates MFMA ----
        if (tid < 256) {
            const int wv = tid >> 6, lane = tid & 63;
            float s = 0.0f;
#pragma unroll
            for (int j = 0; j < 4; ++j) {
                const int m = lane + 64 * j;
                s += (ctxp[0][wv][m] + ctxp[1][wv][m] + ctxp[2][wv][m] + ctxp[3][wv][m]) * wt1s[m];
            }
            for (int o = 32; o > 0; o >>= 1) s += __shfl_xor(s, o, 64);
            if (lane == 0)
                yts[wv] = s + wt_b[0] + wt_w[0] * dec_data[(long)(b0 + wv) * 128 + td];
        }
        f32x4 ga[8];
#pragma unroll
        for (int tt2 = 0; tt2 < 8; ++tt2) {
            const int q = tt2 >> 1, uh = tt2 & 1;
            const float4 b4 = *(const float4*)&dbsum[q * 256 + w * 32 + uh * 16 + kq * 4];
            ga[tt2][0] = b4.x; ga[tt2][1] = b4.y; ga[tt2][2] = b4.z; ga[tt2][3] = b4.w;
        }
        for (int kb = 0; kb < 8; ++kb) {
            const int ko = kb * 32 + kq * 8;     // d region
            const bf16x8 bh = ld_bf8(&sd_hi[r_][ko]);
            const bf16x8 bl = ld_bf8(&sd_lo[r_][ko]);
            const ushort_t* gf = GdF + (((long)kb * 64 + w * 8) * 64 + l) * 8;
#pragma unroll
            for (int tt2 = 0; tt2 < 8; ++tt2) {
                const bf16x8 a = ld_bf8(gf + (long)tt2 * 512);
                ga[tt2] = MFMA_B16(a, bh, ga[tt2]);
                ga[tt2] = MFMA_B16(a, bl, ga[tt2]);
            }
        }
        __syncthreads();   // sd reads + yts writes complete
        // ---- LSTM epilogue ----
        if (r_ < 4) {
            const float yr = yts[r_];
#pragma unroll
            for (int uh = 0; uh < 2; ++uh) {
                const int ub = w * 32 + uh * 16 + kq * 4;
                ushort_t dh[4], dl[4], sh[4], sl[4];
#pragma unroll
                for (int reg = 0; reg < 4; ++reg) {
                    const int u = ub + reg;
                    const float4 wy4 = *(const float4*)&wy[u * 4];
                    const float iv = sig_fast(ga[uh][reg] + wy4.x * yr);
                    const float fv = sig_fast(ga[2 + uh][reg] + wy4.y * yr);
                    const float gv = tanh_fast(ga[4 + uh][reg] + wy4.z * yr);
                    const float ov = sig_fast(ga[6 + uh][reg] + wy4.w * yr);
                    const float sn = fv * cell[uh][reg] + iv * gv;
                    const float dn = ov * tanh_fast(sn);
                    cell[uh][reg] = sn;
                    dh[reg] = f2bf(dn); dl[reg] = f2bf(dn - bf2f(dh[reg]));
                    sh[reg] = f2bf(sn); sl[reg] = f2bf(sn - bf2f(sh[reg]));
                    if (td == 126) dsf[u][r_] = dn;
                }
                *(ushort4*)&sd_hi[r_][ub]       = make_ushort4(dh[0], dh[1], dh[2], dh[3]);
                *(ushort4*)&sd_lo[r_][ub]       = make_ushort4(dl[0], dl[1], dl[2], dl[3]);
                *(ushort4*)&sd_hi[r_][256 + ub] = make_ushort4(sh[0], sh[1], sh[2], sh[3]);
                *(ushort4*)&sd_lo[r_][256 + ub] = make_ushort4(sl[0], sl[1], sl[2], sl[3]);
            }
        }
        __syncthreads();
    }
    // ---- final ctx combine (once) ----
    if (tid < 256) {
        const int m = tid;
        float cr[4];
#pragma unroll
        for (int r = 0; r < 4; ++r)
            cr[r] = ctxp[0][r][m] + ctxp[1][r][m] + ctxp[2][r][m] + ctxp[3][r][m];
        *(float4*)ctx4[m] = make_float4(cr[0], cr[1], cr[2], cr[3]);
    }
    __syncthreads();
    // ---- final MLP: l1 (k-split 2 via scp scratch), relu, l2 reduce ----
    {
        float* scr = &scp[0][0][0];               // reuse as [2][4][256]
        const int ks = tid >> 8, u = tid & 255;
        const float* src = l1T + (long)ks * 256 * 256;
        float a0 = 0, a1 = 0, a2 = 0, a3 = 0;
#pragma unroll 4
        for (int k = 0; k < 256; ++k) {
            const float wv = src[k * 256 + u];
            const float4 q = (ks == 0) ? *(const float4*)dsf[k]
                                       : *(const float4*)ctx4[k];
            a0 = fmaf(q.x, wv, a0); a1 = fmaf(q.y, wv, a1);
            a2 = fmaf(q.z, wv, a2); a3 = fmaf(q.w, wv, a3);
        }
        scr[(ks * 4 + 0) * 256 + u] = a0;
        scr[(ks * 4 + 1) * 256 + u] = a1;
        scr[(ks * 4 + 2) * 256 + u] = a2;
        scr[(ks * 4 + 3) * 256 + u] = a3;
    }
    __syncthreads();
    if (tid < 256) {
        const float* scr = &scp[0][0][0];
        const float bb = l1_b[tid];
        *(float4*)o14[tid] = make_float4(
            fmaxf(scr[0 * 256 + tid] + scr[4 * 256 + tid] + bb, 0.f),
            fmaxf(scr[1 * 256 + tid] + scr[5 * 256 + tid] + bb, 0.f),
            fmaxf(scr[2 * 256 + tid] + scr[6 * 256 + tid] + bb, 0.f),
            fmaxf(scr[3 * 256 + tid] + scr[7 * 256 + tid] + bb, 0.f));
    }
    __syncthreads();
    if (tid < 256) {
        const int wv = tid >> 6, lane = tid & 63;
        float s = o14[lane][wv] * l2s[lane]
                + o14[lane + 64][wv] * l2s[lane + 64]
                + o14[lane + 128][wv] * l2s[lane + 128]
                + o14[lane + 192][wv] * l2s[lane + 192];
        for (int o = 32; o > 0; o >>= 1) s += __shfl_xor(s, o, 64);
        if (lane == 0) out[b0 + wv] = s + l2_b[0];
    }
}

extern "C" void kernel_launch(void* const* d_in, const int* in_sizes, int n_in,
                              void* d_out, int out_size, void* d_ws, size_t ws_size,
                              hipStream_t stream)
{
    const float* enc_data = (const float*)d_in[0];
    const float* dec_data = (const float*)d_in[1];
    const float* enc_Wih  = (const float*)d_in[2];
    const float* enc_Whh  = (const float*)d_in[3];
    const float* enc_bih  = (const float*)d_in[4];
    const float* enc_bhh  = (const float*)d_in[5];
    const float* We   = (const float*)d_in[6];
    const float* Ue   = (const float*)d_in[7];
    const float* ve   = (const float*)d_in[8];
    const float* Wd   = (const float*)d_in[9];
    const float* Ud   = (const float*)d_in[10];
    const float* vd   = (const float*)d_in[11];
    const float* wt_w = (const float*)d_in[12];
    const float* wt_b = (const float*)d_in[13];
    const float* dec_Wih = (const float*)d_in[14];
    const float* dec_Whh = (const float*)d_in[15];
    const float* dec_bih = (const float*)d_in[16];
    const float* dec_bhh = (const float*)d_in[17];
    const float* l1_w = (const float*)d_in[18];
    const float* l1_b = (const float*)d_in[19];
    const float* l2_w = (const float*)d_in[20];
    const float* l2_b = (const float*)d_in[21];

    // ---- workspace layout (~162 MB) ----
    ushort_t* Dbf  = (ushort_t*)d_ws;                         // 1024*128*128
    ushort_t* Hbf  = Dbf + (long)BATCH * TT * NN;             // 1024*128*256
    ushort_t* UHbf = Hbf + (long)BATCH * TT * MM;             // 1024*256*128
    ushort_t* WqeF = UHbf + (long)BATCH * MM * TT;            // 512*128
    ushort_t* WqdF = WqeF + 512 * 128;                        // 512*256
    ushort_t* GeF  = WqdF + 512 * 256;                        // 384*1024
    ushort_t* GdF  = GeF + 384 * 1024;                        // 256*1024
    float* fbase = (float*)(GdF + 256 * 1024);
    float* ebsum = fbase;                                     // 1024
    float* dbsum = ebsum + 1024;                              // 1024
    float* wy    = dbsum + 1024;                              // 1024
    float* l1T   = wy + 1024;                                 // 512*256

    // ---- weight prep ----
    pack_frag_k<<<(512 * 8 * 16 + 255) / 256, 256, 0, stream>>>(
        We, 512, 512, nullptr, 0, 512, 8, 0, WqeF);
    pack_frag_k<<<(512 * 16 * 16 + 255) / 256, 256, 0, stream>>>(
        Wd, 512, 512, nullptr, 0, 512, 16, 0, WqdF);
    pack_frag_k<<<(384 * 64 * 16 + 255) / 256, 256, 0, stream>>>(
        enc_Wih, 128, 128, enc_Whh, 256, 384, 64, 1, GeF);
    pack_frag_k<<<(256 * 64 * 16 + 255) / 256, 256, 0, stream>>>(
        dec_Whh, 256, 256, nullptr, 0, 256, 64, 1, GdF);
    prep_misc_k<<<4, 256, 0, stream>>>(enc_bih, enc_bhh, dec_bih, dec_bhh,
                                       dec_Wih, ebsum, dbsum, wy);
    transpose_k<<<(256 * 512 + 255) / 256, 256, 0, stream>>>(l1_w, l1T, 256, 512);

    // D[b][s][n] = sum_t Ue[s][t] * enc_data[b][t][n]
    gemm_k<false, true, true, false><<<dim3(NN / 64, TT / 64, BATCH), 256, 0, stream>>>(
        Ue, TT, 0, TT,
        nullptr, 0, 0,
        enc_data, NN, (long)TT * NN,
        nullptr, 0,
        nullptr,
        Dbf, NN, (long)TT * NN);

    enc_persist<<<256, 512, 0, stream>>>(enc_data, Dbf, WqeF, GeF, ebsum, ve, Hbf);

    // UH2[b][u][t'] = sum_m Ud[u][m] * H[b][t'][m]
    gemm_k<true, false, true, false><<<dim3(TT / 64, MM / 64, BATCH), 256, 0, stream>>>(
        Ud, MM, 0, MM,
        nullptr, 0, 0,
        Hbf, MM, (long)TT * MM,
        nullptr, 0,
        nullptr,
        UHbf, TT, (long)MM * TT);

    dec_persist<<<256, 512, 0, stream>>>(dec_data, UHbf, Hbf, WqdF, GdF,
                                         dbsum, wy, vd, wt_w, wt_b,
                                         l1T, l1_b, l2_w, l2_b, (float*)d_out);
}